// Round 4
// baseline (982.737 us; speedup 1.0000x reference)
//
#include <hip/hip_runtime.h>

// h_t = alpha_t * h_{t-1} + x_t along S, per (batch, channel). B=4, S=8192, D=1024 fp32.
// Single-pass chunked scan with DEDICATED SEQUENTIAL SWEEPERS (one per batch):
//   - data block (b,c): loads its 16-row chunk fully into registers (32 indep dwordx4 ->
//     deep MLP), local scan, publishes (X,A) aggregate, waits for its prefix flag,
//     emits output. No lookback walk.
//   - sweeper block b: processes chunk aggregates of batch b IN ORDER, 8 at a time
//     (parallel loads, 8 serial fmas), stores exclusive prefixes, sets flag=2.
//     Serial cost ~0.5us per 8 chunks => trails aggregate production by ~1 group.
//   - ticket => start order: sweepers grab tickets 0..3 (resident first); data blocks
//     publish aggregates unconditionally => no circular wait => deadlock-free.
constexpr int B  = 4;
constexpr int S  = 8192;
constexpr int D  = 1024;
constexpr int C  = 512;        // chunks per batch
constexpr int L  = S / C;      // 16 rows per chunk (32 float4 of register state/thread)
constexpr int D4 = D / 4;      // 256 float4 per row = one 256-thread block
constexpr int R  = B * C;      // 2048 data records
constexpr int PD = 8;          // sweeper group depth

typedef float nt_float4 __attribute__((ext_vector_type(4)));

// 8-byte agent-scope (cross-XCD coherent) accessors for lookback state.
__device__ __forceinline__ void store2(unsigned long long* p, float a, float b) {
    union { float f[2]; unsigned long long u; } v; v.f[0] = a; v.f[1] = b;
    __hip_atomic_store(p, v.u, __ATOMIC_RELAXED, __HIP_MEMORY_SCOPE_AGENT);
}
__device__ __forceinline__ void load2(unsigned long long* p, float& a, float& b) {
    union { float f[2]; unsigned long long u; } v;
    v.u = __hip_atomic_load(p, __ATOMIC_RELAXED, __HIP_MEMORY_SCOPE_AGENT);
    a = v.f[0]; b = v.f[1];
}

__global__ __launch_bounds__(256, 2) void scan_sweep(const float4* __restrict__ x,
                                                     const float4* __restrict__ a,
                                                     float4* __restrict__ out,
                                                     unsigned long long* __restrict__ Xagg,
                                                     unsigned long long* __restrict__ Aagg,
                                                     unsigned long long* __restrict__ Carr,
                                                     int* __restrict__ flags,
                                                     int* __restrict__ ticket) {
    const int t = threadIdx.x;
    __shared__ int svid;
    if (t == 0) svid = atomicAdd(ticket, 1);   // device-scope; ticket order == start order
    __syncthreads();
    const int vid = svid;

    if (vid < B) {
        // ---------------- Sweeper for batch b: serial scan over chunk aggregates ----------------
        const int b  = vid;
        const int r0 = b * C;
        float4 carry = {0.f, 0.f, 0.f, 0.f};
        for (int g = 0; g < C; g += PD) {
            if (t == 0) {                       // wait until all PD aggregates of this group exist
                for (int j = 0; j < PD; ++j)
                    while (__hip_atomic_load(&flags[r0 + g + j], __ATOMIC_RELAXED,
                                             __HIP_MEMORY_SCOPE_AGENT) == 0)
                        __builtin_amdgcn_s_sleep(2);
            }
            __syncthreads();
            float4 Xk[PD], Ak[PD];              // PD parallel aggregate loads (fully unrolled)
            #pragma unroll
            for (int j = 0; j < PD; ++j) {
                const long o = ((long)(r0 + g + j) * D4 + t) * 2;
                load2(Xagg + o, Xk[j].x, Xk[j].y); load2(Xagg + o + 1, Xk[j].z, Xk[j].w);
                load2(Aagg + o, Ak[j].x, Ak[j].y); load2(Aagg + o + 1, Ak[j].z, Ak[j].w);
            }
            #pragma unroll
            for (int j = 0; j < PD; ++j) {      // serial part: PD fmas per lane
                const long o = ((long)(r0 + g + j) * D4 + t) * 2;
                store2(Carr + o,     carry.x, carry.y);   // exclusive prefix for chunk g+j
                store2(Carr + o + 1, carry.z, carry.w);
                carry.x = fmaf(Ak[j].x, carry.x, Xk[j].x);
                carry.y = fmaf(Ak[j].y, carry.y, Xk[j].y);
                carry.z = fmaf(Ak[j].z, carry.z, Xk[j].z);
                carry.w = fmaf(Ak[j].w, carry.w, Xk[j].w);
            }
            __syncthreads();                    // drains vmcnt: prefixes visible before flags
            if (t == 0) {
                #pragma unroll
                for (int j = 0; j < PD; ++j)
                    __hip_atomic_store(&flags[r0 + g + j], 2, __ATOMIC_RELEASE,
                                       __HIP_MEMORY_SCOPE_AGENT);
            }
        }
        return;
    }

    // ---------------- Data block: one (batch, chunk), chunk held in registers ----------------
    const int vd = vid - B;
    const int b  = vd & (B - 1);               // round-robin over batches => chunks start in order
    const int c  = vd >> 2;
    const int r  = b * C + c;
    const long base = ((long)(b * S + c * L)) * D4 + t;

    float4 Xs[L], Ps[L];                       // 32 independent dwordx4 in flight
    #pragma unroll
    for (int s = 0; s < L; ++s) {
        Xs[s] = x[base + (long)s * D4];
        Ps[s] = a[base + (long)s * D4];
    }
    // In-place zero-carry scan: Xs[s] = h_s(h_in=0), Ps[s] = prod(alpha_0..s).
    #pragma unroll
    for (int s = 1; s < L; ++s) {
        Xs[s].x = fmaf(Ps[s].x, Xs[s-1].x, Xs[s].x);
        Xs[s].y = fmaf(Ps[s].y, Xs[s-1].y, Xs[s].y);
        Xs[s].z = fmaf(Ps[s].z, Xs[s-1].z, Xs[s].z);
        Xs[s].w = fmaf(Ps[s].w, Xs[s-1].w, Xs[s].w);
        Ps[s].x *= Ps[s-1].x; Ps[s].y *= Ps[s-1].y;
        Ps[s].z *= Ps[s-1].z; Ps[s].w *= Ps[s-1].w;
    }

    // Publish aggregate (flag=1). All chunks publish (sweeper consumes even c==0's).
    {
        const long o = ((long)r * D4 + t) * 2;
        store2(Xagg + o,     Xs[L-1].x, Xs[L-1].y);
        store2(Xagg + o + 1, Xs[L-1].z, Xs[L-1].w);
        store2(Aagg + o,     Ps[L-1].x, Ps[L-1].y);
        store2(Aagg + o + 1, Ps[L-1].z, Ps[L-1].w);
    }
    __syncthreads();                            // drain vmcnt before flag store
    if (t == 0) __hip_atomic_store(&flags[r], 1, __ATOMIC_RELEASE, __HIP_MEMORY_SCOPE_AGENT);

    // Wait for the sweeper's exclusive prefix (c==0 knows it is zero).
    float4 carry = {0.f, 0.f, 0.f, 0.f};
    if (c > 0) {
        while (__hip_atomic_load(&flags[r], __ATOMIC_RELAXED, __HIP_MEMORY_SCOPE_AGENT) != 2)
            __builtin_amdgcn_s_sleep(8);
        const long o = ((long)r * D4 + t) * 2;
        load2(Carr + o,     carry.x, carry.y);
        load2(Carr + o + 1, carry.z, carry.w);
    }

    // Final: h_s = Xs[s] + Ps[s]*carry. Nontemporal (out never re-read).
    nt_float4* ntout = (nt_float4*)out;
    #pragma unroll
    for (int s = 0; s < L; ++s) {
        nt_float4 hv = { fmaf(Ps[s].x, carry.x, Xs[s].x),
                         fmaf(Ps[s].y, carry.y, Xs[s].y),
                         fmaf(Ps[s].z, carry.z, Xs[s].z),
                         fmaf(Ps[s].w, carry.w, Xs[s].w) };
        __builtin_nontemporal_store(hv, &ntout[base + (long)s * D4]);
    }
}

extern "C" void kernel_launch(void* const* d_in, const int* in_sizes, int n_in,
                              void* d_out, int out_size, void* d_ws, size_t ws_size,
                              hipStream_t stream) {
    const float4* x = (const float4*)d_in[0];
    const float4* a = (const float4*)d_in[1];
    float4* out = (float4*)d_out;

    // Workspace: [ticket | pad | flags R*4B] (16 KiB, zeroed each launch)
    //            | Xagg 8 MiB | Aagg 8 MiB | Carr 8 MiB => 24 MiB + 16 KiB.
    char* ws = (char*)d_ws;
    int* ticket = (int*)ws;
    int* flags  = (int*)(ws + 256);
    unsigned long long* Xagg = (unsigned long long*)(ws + 16384);
    unsigned long long* Aagg = Xagg + (size_t)R * D4 * 2;
    unsigned long long* Carr = Aagg + (size_t)R * D4 * 2;

    hipMemsetAsync(ws, 0, 16384, stream);       // reset ticket + flags (graph-capturable)
    scan_sweep<<<dim3(R + B), 256, 0, stream>>>(x, a, out, Xagg, Aagg, Carr, flags, ticket);
}

// Round 5
// 430.185 us; speedup vs baseline: 2.2845x; 2.2845x over previous
//
#include <hip/hip_runtime.h>

// h_t = alpha_t*h_{t-1} + x_t along S per (b,d). B=4, S=8192, D=1024, fp32.
// Cooperative-style single-load structure with SOFTWARE GRID BARRIER:
//   grid = 256 blocks (1/CU, all co-resident) x 256 threads.
//   Block (b,c) owns chunk c (L=128 rows) of batch b; thread owns 4 channels.
//   Pass A: stream chunk (double-buffered, ~32 dwordx4 in flight), aggregate (X,A).
//   barrier; 16 blocks sweep the 64-chunk carry chains (1 thread/channel, pipelined);
//   barrier; Pass B: re-read chunk (L3-hot), seed with prefix, NT-store output.
// Serial cross-block latency: 2 barriers + one 64-deep pipelined chain (~5us),
// vs rounds 3/4's 512 chained memory round-trips.
constexpr int B    = 4;
constexpr int S    = 8192;
constexpr int D    = 1024;
constexpr int CB   = 64;         // chunks per batch
constexpr int L    = S / CB;     // 128 rows per chunk
constexpr int D4   = D / 4;      // 256 float4 per row = one 256-thread block
constexpr int NBLK = B * CB;     // 256 blocks total = 1 per CU
constexpr int G    = 8;          // rows per load group
constexpr int NG   = L / G;      // 16 groups per chunk

typedef float nt_float4 __attribute__((ext_vector_type(4)));

// Agent-scope (cross-XCD coherent) 4B accessors for the small shared state.
__device__ __forceinline__ void ast(float* p, float v) {
    __hip_atomic_store(p, v, __ATOMIC_RELAXED, __HIP_MEMORY_SCOPE_AGENT);
}
__device__ __forceinline__ float ald(const float* p) {
    return __hip_atomic_load(p, __ATOMIC_RELAXED, __HIP_MEMORY_SCOPE_AGENT);
}

// Software grid barrier: all NBLK blocks are co-resident by construction.
__device__ __forceinline__ void gridbar(int* bar) {
    __syncthreads();                       // drains vmcnt: block's stores complete first
    if (threadIdx.x == 0) {
        __hip_atomic_fetch_add(bar, 1, __ATOMIC_ACQ_REL, __HIP_MEMORY_SCOPE_AGENT);
        while (__hip_atomic_load(bar, __ATOMIC_RELAXED, __HIP_MEMORY_SCOPE_AGENT) < NBLK)
            __builtin_amdgcn_s_sleep(2);
        __threadfence();                   // acquire: invalidate stale L1/L2 lines
    }
    __syncthreads();
}

__device__ __forceinline__ void issue_grp(const float4* __restrict__ x,
                                          const float4* __restrict__ a,
                                          long o, float4 (&bx)[G], float4 (&ba)[G]) {
    #pragma unroll
    for (int j = 0; j < G; ++j) {
        bx[j] = x[o + (long)j * D4];
        ba[j] = a[o + (long)j * D4];
    }
}

__global__ __launch_bounds__(256, 1) void scan_coop(const float4* __restrict__ x,
                                                    const float4* __restrict__ a,
                                                    float4* __restrict__ out,
                                                    float* __restrict__ Xagg,
                                                    float* __restrict__ Aagg,
                                                    float* __restrict__ Pref,
                                                    int* __restrict__ bars) {
    const int t   = threadIdx.x;
    const int bid = blockIdx.x;
    const int b   = bid >> 6;              // batch (CB=64)
    const int c   = bid & (CB - 1);        // chunk
    const long base = ((long)(b * S + c * L)) * D4 + t;

    float4 bx0[G], ba0[G], bx1[G], ba1[G];

    // ---------------- Pass A: stream chunk, compute (X, A) aggregate ----------------
    float4 X = {0.f, 0.f, 0.f, 0.f};
    float4 A = {1.f, 1.f, 1.f, 1.f};
    issue_grp(x, a, base, bx0, ba0);
    #pragma unroll
    for (int g = 0; g < NG; g += 2) {
        issue_grp(x, a, base + (long)(g + 1) * G * D4, bx1, ba1);   // g+1 <= 15
        #pragma unroll
        for (int j = 0; j < G; ++j) {
            X.x = fmaf(ba0[j].x, X.x, bx0[j].x); A.x *= ba0[j].x;
            X.y = fmaf(ba0[j].y, X.y, bx0[j].y); A.y *= ba0[j].y;
            X.z = fmaf(ba0[j].z, X.z, bx0[j].z); A.z *= ba0[j].z;
            X.w = fmaf(ba0[j].w, X.w, bx0[j].w); A.w *= ba0[j].w;
        }
        if (g + 2 < NG) issue_grp(x, a, base + (long)(g + 2) * G * D4, bx0, ba0);
        #pragma unroll
        for (int j = 0; j < G; ++j) {
            X.x = fmaf(ba1[j].x, X.x, bx1[j].x); A.x *= ba1[j].x;
            X.y = fmaf(ba1[j].y, X.y, bx1[j].y); A.y *= ba1[j].y;
            X.z = fmaf(ba1[j].z, X.z, bx1[j].z); A.z *= ba1[j].z;
            X.w = fmaf(ba1[j].w, X.w, bx1[j].w); A.w *= ba1[j].w;
        }
    }
    {   // publish aggregates: layout [r][D], r = bid, channels d = 4t..4t+3
        float* Xp = Xagg + (long)bid * D + 4 * t;
        float* Ap = Aagg + (long)bid * D + 4 * t;
        ast(Xp + 0, X.x); ast(Xp + 1, X.y); ast(Xp + 2, X.z); ast(Xp + 3, X.w);
        ast(Ap + 0, A.x); ast(Ap + 1, A.y); ast(Ap + 2, A.z); ast(Ap + 3, A.w);
    }

    gridbar(bars + 0);

    // ---------------- Sweep: 16 blocks, 1 thread per (batch, channel) ----------------
    if (bid < 16) {
        const int gg = bid * 256 + t;      // 0..4095
        const int sb = gg >> 10;           // batch
        const int d  = gg & (D - 1);       // channel
        const float* Xp = Xagg + (long)sb * CB * D + d;   // stride D along chunks
        const float* Ap = Aagg + (long)sb * CB * D + d;
        float*       Pp = Pref + (long)sb * CB * D + d;
        float carry = 0.f;
        for (int cc = 0; cc < CB; cc += 8) {
            float xv[8], av[8];
            #pragma unroll
            for (int j = 0; j < 8; ++j) {  // 16 independent loads in flight
                xv[j] = ald(Xp + (long)(cc + j) * D);
                av[j] = ald(Ap + (long)(cc + j) * D);
            }
            #pragma unroll
            for (int j = 0; j < 8; ++j) {  // serial part: 8 fmas
                ast(Pp + (long)(cc + j) * D, carry);      // exclusive prefix
                carry = fmaf(av[j], carry, xv[j]);
            }
        }
    }

    gridbar(bars + 1);

    // ---------------- Pass B: re-read chunk (L3-hot), emit with carry ----------------
    float4 h;
    {
        const float* Pp = Pref + (long)bid * D + 4 * t;
        h.x = ald(Pp + 0); h.y = ald(Pp + 1); h.z = ald(Pp + 2); h.w = ald(Pp + 3);
    }
    nt_float4* ntout = (nt_float4*)out;
    issue_grp(x, a, base, bx0, ba0);
    #pragma unroll
    for (int g = 0; g < NG; g += 2) {
        issue_grp(x, a, base + (long)(g + 1) * G * D4, bx1, ba1);
        #pragma unroll
        for (int j = 0; j < G; ++j) {
            h.x = fmaf(ba0[j].x, h.x, bx0[j].x);
            h.y = fmaf(ba0[j].y, h.y, bx0[j].y);
            h.z = fmaf(ba0[j].z, h.z, bx0[j].z);
            h.w = fmaf(ba0[j].w, h.w, bx0[j].w);
            nt_float4 hv = {h.x, h.y, h.z, h.w};
            __builtin_nontemporal_store(hv, &ntout[base + (long)(g * G + j) * D4]);
        }
        if (g + 2 < NG) issue_grp(x, a, base + (long)(g + 2) * G * D4, bx0, ba0);
        #pragma unroll
        for (int j = 0; j < G; ++j) {
            h.x = fmaf(ba1[j].x, h.x, bx1[j].x);
            h.y = fmaf(ba1[j].y, h.y, bx1[j].y);
            h.z = fmaf(ba1[j].z, h.z, bx1[j].z);
            h.w = fmaf(ba1[j].w, h.w, bx1[j].w);
            nt_float4 hv = {h.x, h.y, h.z, h.w};
            __builtin_nontemporal_store(hv, &ntout[base + (long)((g + 1) * G + j) * D4]);
        }
    }
}

extern "C" void kernel_launch(void* const* d_in, const int* in_sizes, int n_in,
                              void* d_out, int out_size, void* d_ws, size_t ws_size,
                              hipStream_t stream) {
    const float4* x = (const float4*)d_in[0];
    const float4* a = (const float4*)d_in[1];
    float4* out = (float4*)d_out;

    // Workspace: [bars 256B] | Xagg 1MB | Aagg 1MB | Pref 1MB  (~3 MiB)
    char* ws = (char*)d_ws;
    int*   bars = (int*)ws;
    float* Xagg = (float*)(ws + 4096);
    float* Aagg = Xagg + (size_t)NBLK * D;
    float* Pref = Aagg + (size_t)NBLK * D;

    hipMemsetAsync(ws, 0, 4096, stream);   // reset barrier counters (graph-capturable)
    scan_coop<<<dim3(NBLK), 256, 0, stream>>>(x, a, out, Xagg, Aagg, Pref, bars);
}